// Round 3
// baseline (297.172 us; speedup 1.0000x reference)
//
#include <hip/hip_runtime.h>

#define TT 2048
#define TS 2048
#define NB 2
#define CC 512
#define NH 8
#define HD 64
#define NCH 4                 // split-K chunks over keys
#define KCH (TS / NCH)        // 512 keys per chunk
#define NROW (NB * NH * TT)   // 32768 (b,h,q) rows

typedef __attribute__((ext_vector_type(8))) short s8v;
typedef __attribute__((ext_vector_type(8))) __bf16 bf8v;
typedef __attribute__((ext_vector_type(4))) float f4v;
typedef __attribute__((ext_vector_type(4))) unsigned short us4;

static __device__ __forceinline__ unsigned short f2bf(float f) {
  unsigned int u = __builtin_bit_cast(unsigned int, f);
  u += 0x7FFFu + ((u >> 16) & 1u);   // round-to-nearest-even
  return (unsigned short)(u >> 16);
}
static __device__ __forceinline__ float bf2f(unsigned short u) {
  return __builtin_bit_cast(float, (unsigned int)u << 16);
}
static __device__ __forceinline__ bf8v ld_bf8(const unsigned short* p) {
  return __builtin_bit_cast(bf8v, *(const s8v*)p);
}
static __device__ __forceinline__ f4v mfma16(bf8v a, bf8v b, f4v c) {
  return __builtin_amdgcn_mfma_f32_16x16x32_bf16(a, b, c, 0, 0, 0);
}
static __device__ __forceinline__ f4v max4(f4v a, f4v b) {
  f4v r;
#pragma unroll
  for (int i = 0; i < 4; i++) r[i] = fmaxf(a[i], b[i]);
  return r;
}

// ---------------- all-4 weight transpose+convert: WT[n][k] = bf16(W[k][n]) ----------------
__global__ __launch_bounds__(256) void wtrans_k(const float* __restrict__ W0,
    const float* __restrict__ W1, const float* __restrict__ W2, const float* __restrict__ W3,
    unsigned short* __restrict__ T0, unsigned short* __restrict__ T1,
    unsigned short* __restrict__ T2, unsigned short* __restrict__ T3) {
  const float* Ws[4] = {W0, W1, W2, W3};
  unsigned short* Ts[4] = {T0, T1, T2, T3};
  const float* W = Ws[blockIdx.z];
  unsigned short* WT = Ts[blockIdx.z];
  __shared__ float t[64][65];
  int i0 = blockIdx.x * 64, j0 = blockIdx.y * 64;
  int tx = threadIdx.x & 63, ty = threadIdx.x >> 6;
#pragma unroll
  for (int r = 0; r < 16; r++) {
    int li = ty * 16 + r;
    t[li][tx] = W[(size_t)(i0 + li) * CC + j0 + tx];
  }
  __syncthreads();
#pragma unroll
  for (int r = 0; r < 16; r++) {
    int lj = ty * 16 + r;
    WT[(size_t)(j0 + lj) * CC + i0 + tx] = f2bf(t[tx][lj]);
  }
}

// ------- f32->bf16 convert for x/enc, plus mask -> float penalty array -------
__global__ __launch_bounds__(256) void cvt_k(const float* __restrict__ x,
    const float* __restrict__ enc, const int* __restrict__ mask,
    unsigned short* __restrict__ xb, unsigned short* __restrict__ eb,
    float* __restrict__ pinf) {
  size_t t = (size_t)blockIdx.x * 256 + threadIdx.x;
  size_t i = t * 4;
  f4v a = *(const f4v*)(x + i);
  f4v b = *(const f4v*)(enc + i);
  us4 pa, pb;
#pragma unroll
  for (int j = 0; j < 4; j++) { pa[j] = f2bf(a[j]); pb[j] = f2bf(b[j]); }
  *(us4*)(xb + i) = pa;
  *(us4*)(eb + i) = pb;
  if (t < NB * TS) pinf[t] = (mask[t] != 0) ? 0.0f : -1e30f;
}

// ---------------- fused QKV GEMM: blockIdx.z selects op ----------------
// 0: Q = xb@Wq (scaled 1/8), 1: K = eb@Wk, 2: V = eb@Wv (transposed store)
__global__ __launch_bounds__(256) void qkv_k(const unsigned short* __restrict__ xb,
    const unsigned short* __restrict__ eb,
    const unsigned short* __restrict__ WqT, const float* __restrict__ bq,
    const unsigned short* __restrict__ WkT, const float* __restrict__ bk,
    const unsigned short* __restrict__ WvT, const float* __restrict__ bv,
    unsigned short* __restrict__ Qb, unsigned short* __restrict__ Kb,
    unsigned short* __restrict__ VTb) {
  int op = blockIdx.z;
  const unsigned short* A = (op == 0) ? xb : eb;
  const unsigned short* WT = (op == 0) ? WqT : (op == 1 ? WkT : WvT);
  const float* bias = (op == 0) ? bq : (op == 1 ? bk : bv);
  int lane = threadIdx.x & 63, wave = threadIdx.x >> 6;
  int quad = lane >> 4, l16 = lane & 15;
  int row0 = blockIdx.x * 64 + wave * 16;
  int n0 = blockIdx.y * 64;
  f4v acc[4] = {{0,0,0,0},{0,0,0,0},{0,0,0,0},{0,0,0,0}};
  const unsigned short* Ap = A + (size_t)(row0 + l16) * CC + quad * 8;
  const unsigned short* Wb = WT + (size_t)(n0 + l16) * CC + quad * 8;
#pragma unroll 4
  for (int k0 = 0; k0 < CC; k0 += 32) {
    bf8v a = ld_bf8(Ap + k0);
#pragma unroll
    for (int nt = 0; nt < 4; nt++)
      acc[nt] = mfma16(a, ld_bf8(Wb + (size_t)nt * 16 * CC + k0), acc[nt]);
  }
  float scale = (op == 0) ? 0.125f : 1.0f;
#pragma unroll
  for (int nt = 0; nt < 4; nt++) {
    int col = n0 + nt * 16 + l16;
    float bcol = bias[col];
    if (op == 2) {
      // VT[b][c][t]: 4 consecutive t per lane -> 8B store
      int rb = row0 + quad * 4;
      int bb = rb >> 11, tt = rb & (TT - 1);
      us4 pk;
#pragma unroll
      for (int r = 0; r < 4; r++) pk[r] = f2bf(acc[nt][r] + bcol);
      *(us4*)(VTb + ((size_t)bb * CC + col) * TS + tt) = pk;
    } else {
      unsigned short* O = (op == 0) ? Qb : Kb;
#pragma unroll
      for (int r = 0; r < 4; r++)
        O[(size_t)(row0 + quad * 4 + r) * CC + col] = f2bf((acc[nt][r] + bcol) * scale);
    }
  }
}

// ---------------- output projection GEMM: out_f32 = Attb @ Wo + bo ----------------
__global__ __launch_bounds__(256) void gemmo_k(const unsigned short* __restrict__ A,
    const unsigned short* __restrict__ WT, const float* __restrict__ bias,
    float* __restrict__ Cout) {
  int lane = threadIdx.x & 63, wave = threadIdx.x >> 6;
  int quad = lane >> 4, l16 = lane & 15;
  int row0 = blockIdx.x * 64 + wave * 16;
  int n0 = blockIdx.y * 64;
  f4v acc[4] = {{0,0,0,0},{0,0,0,0},{0,0,0,0},{0,0,0,0}};
  const unsigned short* Ap = A + (size_t)(row0 + l16) * CC + quad * 8;
  const unsigned short* Wb = WT + (size_t)(n0 + l16) * CC + quad * 8;
#pragma unroll 4
  for (int k0 = 0; k0 < CC; k0 += 32) {
    bf8v a = ld_bf8(Ap + k0);
#pragma unroll
    for (int nt = 0; nt < 4; nt++)
      acc[nt] = mfma16(a, ld_bf8(Wb + (size_t)nt * 16 * CC + k0), acc[nt]);
  }
#pragma unroll
  for (int nt = 0; nt < 4; nt++) {
    int col = n0 + nt * 16 + l16;
    float bcol = bias[col];
#pragma unroll
    for (int r = 0; r < 4; r++)
      Cout[(size_t)(row0 + quad * 4 + r) * CC + col] = acc[nt][r] + bcol;
  }
}

// ---------------- split-K flash attention (S^T / O^T orientation) ----------------
// grid (TT/64, NB*NH, NCH), block 256. Each wave: 16 q vs KCH keys.
// Lane owns q = l16; scores for that q live in-lane (keys nt*16+quad*4+r).
__global__ __launch_bounds__(256) void attn_k(const unsigned short* __restrict__ Q,
    const unsigned short* __restrict__ K, const unsigned short* __restrict__ VT,
    const float* __restrict__ pinf, unsigned short* __restrict__ Op,
    float* __restrict__ Mp, float* __restrict__ Lp) {
  __shared__ unsigned short Pl[4][16][72];  // wave-private P[q][key], +8 pad
  int lane = threadIdx.x & 63, wave = threadIdx.x >> 6;
  int quad = lane >> 4, l16 = lane & 15;
  int bh = blockIdx.y;
  int b = bh >> 3, h = bh & 7;
  int chunk = blockIdx.z;
  int q0 = blockIdx.x * 64 + wave * 16;

  const unsigned short* qp = Q + (size_t)(b * TT + q0 + l16) * CC + h * HD + quad * 8;
  bf8v qa0 = ld_bf8(qp), qa1 = ld_bf8(qp + 32);

  f4v o[4] = {{0,0,0,0},{0,0,0,0},{0,0,0,0},{0,0,0,0}};
  float m = -1e30f, l = 0.f;
  const float* prow = pinf + (size_t)b * TS + chunk * KCH;
  const unsigned short* Kbase =
      K + (size_t)(b * TS + chunk * KCH) * CC + h * HD + quad * 8;
  const unsigned short* Vbase =
      VT + ((size_t)b * CC + h * HD) * TS + chunk * KCH + quad * 8;

  for (int kt = 0; kt < KCH; kt += 64) {
    // S^T = K·Q^T + pen  (operand swap: A=K-frag, B=Q-frag)
    f4v s[4];
#pragma unroll
    for (int nt = 0; nt < 4; nt++) {
      const unsigned short* kp = Kbase + (size_t)(kt + nt * 16 + l16) * CC;
      f4v z = *(const f4v*)(prow + kt + nt * 16 + quad * 4);  // penalty as acc-init
      z = mfma16(ld_bf8(kp), qa0, z);
      z = mfma16(ld_bf8(kp + 32), qa1, z);
      s[nt] = z;
    }
    // in-lane softmax for q=l16: 16 scores per lane, 2 shuffles per reduction
    f4v m4 = max4(max4(s[0], s[1]), max4(s[2], s[3]));
    float mx = fmaxf(fmaxf(m4[0], m4[1]), fmaxf(m4[2], m4[3]));
    mx = fmaxf(mx, __shfl_xor(mx, 16, 64));
    mx = fmaxf(mx, __shfl_xor(mx, 32, 64));
    float mnew = fmaxf(m, mx);
    float alpha = __expf(m - mnew);
    f4v rs4 = {0, 0, 0, 0};
#pragma unroll
    for (int nt = 0; nt < 4; nt++) {
#pragma unroll
      for (int r = 0; r < 4; r++) s[nt][r] = __expf(s[nt][r] - mnew);
      rs4 += s[nt];
    }
    float rs = (rs4[0] + rs4[1]) + (rs4[2] + rs4[3]);
    rs += __shfl_xor(rs, 16, 64);
    rs += __shfl_xor(rs, 32, 64);
    l = l * alpha + rs;
    m = mnew;
#pragma unroll
    for (int dt = 0; dt < 4; dt++) o[dt] *= alpha;   // alpha per-lane scalar
    // P[q][key]: lane's 4 r-keys are contiguous -> packed 8B LDS writes
#pragma unroll
    for (int nt = 0; nt < 4; nt++) {
      us4 pk;
#pragma unroll
      for (int r = 0; r < 4; r++) pk[r] = f2bf(s[nt][r]);
      *(us4*)&Pl[wave][l16][nt * 16 + quad * 4] = pk;
    }
    bf8v pb0 = ld_bf8(&Pl[wave][l16][quad * 8]);
    bf8v pb1 = ld_bf8(&Pl[wave][l16][32 + quad * 8]);
    // O^T += V^T·P^T  (operand swap: A=V-frag, B=P-frag)
#pragma unroll
    for (int dt = 0; dt < 4; dt++) {
      const unsigned short* vp = Vbase + (size_t)(dt * 16 + l16) * TS + kt;
      o[dt] = mfma16(ld_bf8(vp), pb0, o[dt]);
      o[dt] = mfma16(ld_bf8(vp + 32), pb1, o[dt]);
    }
  }
  // o[dt][r] = O[q=l16][d=dt*16+quad*4+r] unnormalized; packed 8B stores
  int rowb = (b * NH + h) * TT + q0;
  size_t obase = (size_t)chunk * NROW * HD + (size_t)(rowb + l16) * HD;
#pragma unroll
  for (int dt = 0; dt < 4; dt++) {
    us4 pk;
#pragma unroll
    for (int r = 0; r < 4; r++) pk[r] = f2bf(o[dt][r]);
    *(us4*)&Op[obase + dt * 16 + quad * 4] = pk;
  }
  if (quad == 0) {
    Mp[(size_t)chunk * NROW + rowb + l16] = m;
    Lp[(size_t)chunk * NROW + rowb + l16] = l;
  }
}

// ---------------- split-K combine: Attb[b][q][h*64+d] ----------------
__global__ __launch_bounds__(256) void combine_k(const unsigned short* __restrict__ Op,
    const float* __restrict__ Mp, const float* __restrict__ Lp,
    unsigned short* __restrict__ Attb) {
  int row = blockIdx.x * 4 + (threadIdx.x >> 6);
  int d = threadIdx.x & 63;
  float m[NCH], l[NCH];
#pragma unroll
  for (int c = 0; c < NCH; c++) {
    m[c] = Mp[(size_t)c * NROW + row];
    l[c] = Lp[(size_t)c * NROW + row];
  }
  float M = fmaxf(fmaxf(m[0], m[1]), fmaxf(m[2], m[3]));
  float L = 0.f, o = 0.f;
#pragma unroll
  for (int c = 0; c < NCH; c++) {
    float w = __expf(m[c] - M);
    L += w * l[c];
    o += w * bf2f(Op[(size_t)c * NROW * HD + (size_t)row * HD + d]);
  }
  int b = row >> 14, h = (row >> 11) & 7, q = row & (TT - 1);
  Attb[((size_t)(b * TT + q)) * CC + h * HD + d] = f2bf(o / L);
}

extern "C" void kernel_launch(void* const* d_in, const int* in_sizes, int n_in,
                              void* d_out, int out_size, void* d_ws, size_t ws_size,
                              hipStream_t stream) {
  const float* x   = (const float*)d_in[0];
  const float* enc = (const float*)d_in[1];
  const int*   msk = (const int*)d_in[2];
  const float* Wq  = (const float*)d_in[3];
  const float* bq  = (const float*)d_in[4];
  const float* Wk  = (const float*)d_in[5];
  const float* bk  = (const float*)d_in[6];
  const float* Wv  = (const float*)d_in[7];
  const float* bv  = (const float*)d_in[8];
  const float* Wo  = (const float*)d_in[9];
  const float* bo  = (const float*)d_in[10];
  float* out = (float*)d_out;

  char* ws = (char*)d_ws;
  const size_t MB = 1024 * 1024;
  unsigned short* WqT  = (unsigned short*)(ws);                 // 512 KB
  unsigned short* WkT  = (unsigned short*)(ws + 512 * 1024);
  unsigned short* WvT  = (unsigned short*)(ws + 1024 * 1024);
  unsigned short* WoT  = (unsigned short*)(ws + 1536 * 1024);
  unsigned short* Qb   = (unsigned short*)(ws + 2 * MB);        // 4 MB
  unsigned short* Kb   = (unsigned short*)(ws + 6 * MB);        // 4 MB
  unsigned short* VTb  = (unsigned short*)(ws + 10 * MB);       // 4 MB
  unsigned short* Attb = (unsigned short*)(ws + 14 * MB);       // 4 MB
  // xb/eb live only until the QKV GEMM; Opart overlays them afterwards
  unsigned short* xb   = (unsigned short*)(ws + 18 * MB);       // 4 MB
  unsigned short* eb   = (unsigned short*)(ws + 22 * MB);       // 4 MB
  unsigned short* Opart = (unsigned short*)(ws + 18 * MB);      // 16 MB (overlay)
  float* Mp   = (float*)(ws + 34 * MB);                         // 512 KB
  float* Lp   = (float*)(ws + 34 * MB + 512 * 1024);            // 512 KB
  float* pinf = (float*)(ws + 35 * MB);                         // 16 KB

  dim3 blk(256);
  wtrans_k<<<dim3(8, 8, 4), blk, 0, stream>>>(Wq, Wk, Wv, Wo, WqT, WkT, WvT, WoT);
  cvt_k<<<dim3(2048), blk, 0, stream>>>(x, enc, msk, xb, eb, pinf);

  qkv_k<<<dim3(64, 8, 3), blk, 0, stream>>>(xb, eb, WqT, bq, WkT, bk, WvT, bv,
                                            Qb, Kb, VTb);

  attn_k<<<dim3(TT / 64, NB * NH, NCH), blk, 0, stream>>>(Qb, Kb, VTb, pinf,
                                                          Opart, Mp, Lp);
  combine_k<<<dim3(NROW / 4), blk, 0, stream>>>(Opart, Mp, Lp, Attb);

  gemmo_k<<<dim3(64, 8), blk, 0, stream>>>(Attb, WoT, bo, out);
}